// Round 3
// baseline (318.834 us; speedup 1.0000x reference)
//
#include <hip/hip_runtime.h>

#define IN_F 128
#define OUT_F 128

static __device__ __forceinline__ unsigned f2bf(float x) {
    unsigned b = __float_as_uint(x);
    return (b + 0x7FFFu + ((b >> 16) & 1u)) >> 16;   // RNE
}
static __device__ __forceinline__ float bfLo(unsigned u) { return __uint_as_float(u << 16); }
static __device__ __forceinline__ float bfHi(unsigned u) { return __uint_as_float(u & 0xFFFF0000u); }

// ---------------- GEMM: seq_b16[N,128] = bf16( A[N,128] @ W[128,128] ) ----------------
__global__ __launch_bounds__(256) void gemm64x128(
    const float* __restrict__ A, const float* __restrict__ W,
    unsigned short* __restrict__ Cb, int nrows)
{
    __shared__ float As[64][65];
    __shared__ float Ws[64][128];
    const int t  = threadIdx.x;
    const int rg = t >> 4;
    const int c0 = (t & 15) * 8;
    const int rowBase = blockIdx.x * 64;

    float acc[4][8];
#pragma unroll
    for (int i = 0; i < 4; ++i)
#pragma unroll
        for (int j = 0; j < 8; ++j) acc[i][j] = 0.f;

    for (int p = 0; p < 2; ++p) {
#pragma unroll
        for (int i = 0; i < 4; ++i) {
            int q  = t + i * 256;
            int r  = q >> 4;
            int k4 = (q & 15) * 4;
            int gr = rowBase + r;
            if (gr >= nrows) gr = nrows - 1;
            const float4 v = *(const float4*)(A + (size_t)gr * IN_F + p * 64 + k4);
            As[r][k4 + 0] = v.x; As[r][k4 + 1] = v.y;
            As[r][k4 + 2] = v.z; As[r][k4 + 3] = v.w;
        }
#pragma unroll
        for (int i = 0; i < 8; ++i) {
            int q  = t + i * 256;
            int k  = q >> 5;
            int c4 = (q & 31) * 4;
            *(float4*)(&Ws[k][c4]) = *(const float4*)(W + (p * 64 + k) * OUT_F + c4);
        }
        __syncthreads();

#pragma unroll 4
        for (int k = 0; k < 64; ++k) {
            float av[4] = {As[rg * 4 + 0][k], As[rg * 4 + 1][k],
                           As[rg * 4 + 2][k], As[rg * 4 + 3][k]};
            float4 w0 = *(const float4*)(&Ws[k][c0]);
            float4 w1 = *(const float4*)(&Ws[k][c0 + 4]);
            float wv[8] = {w0.x, w0.y, w0.z, w0.w, w1.x, w1.y, w1.z, w1.w};
#pragma unroll
            for (int i = 0; i < 4; ++i)
#pragma unroll
                for (int j = 0; j < 8; ++j)
                    acc[i][j] = fmaf(av[i], wv[j], acc[i][j]);
        }
        __syncthreads();
    }

#pragma unroll
    for (int i = 0; i < 4; ++i) {
        int gr = rowBase + rg * 4 + i;
        if (gr < nrows) {
            uint4 pk;
            pk.x = f2bf(acc[i][0]) | (f2bf(acc[i][1]) << 16);
            pk.y = f2bf(acc[i][2]) | (f2bf(acc[i][3]) << 16);
            pk.z = f2bf(acc[i][4]) | (f2bf(acc[i][5]) << 16);
            pk.w = f2bf(acc[i][6]) | (f2bf(acc[i][7]) << 16);
            *(uint4*)(Cb + (size_t)gr * OUT_F + c0) = pk;
        }
    }
}

// ---------------- bucket CSR build (bucket = 32 nodes) ----------------
__global__ void zerob_kernel(int* __restrict__ c, int n)
{
    int i = blockIdx.x * 256 + threadIdx.x;
    if (i < n) c[i] = 0;
}

__global__ void histb_kernel(const int* __restrict__ row, int* __restrict__ cnt, int E)
{
    int i = (blockIdx.x * 256 + threadIdx.x) * 4;
    if (i + 3 < E) {
        int4 r = *(const int4*)(row + i);
        atomicAdd(&cnt[r.x >> 5], 1); atomicAdd(&cnt[r.y >> 5], 1);
        atomicAdd(&cnt[r.z >> 5], 1); atomicAdd(&cnt[r.w >> 5], 1);
    } else {
        for (; i < E; ++i) atomicAdd(&cnt[row[i] >> 5], 1);
    }
}

// single block, 1024 threads, 2 items/thread: exclusive scan of bucket counts
__global__ __launch_bounds__(1024) void scan2_kernel(const int* __restrict__ bsum,
                                                     int* __restrict__ boff,
                                                     int* __restrict__ cur, int NBK)
{
    __shared__ int s[1024];
    int t = threadIdx.x;
    int i0 = 2 * t, i1 = 2 * t + 1;
    int v0 = (i0 < NBK) ? bsum[i0] : 0;
    int v1 = (i1 < NBK) ? bsum[i1] : 0;
    int sum = v0 + v1;
    s[t] = sum;
    __syncthreads();
    for (int o = 1; o < 1024; o <<= 1) {
        int x = (t >= o) ? s[t - o] : 0;
        __syncthreads();
        s[t] += x;
        __syncthreads();
    }
    int base = s[t] - sum;   // exclusive
    if (i0 <= NBK) { boff[i0] = base;      if (i0 < NBK) cur[i0] = base; }
    if (i1 <= NBK) { boff[i1] = base + v0; if (i1 < NBK) cur[i1] = base + v0; }
}

// append packed records into bucket regions (dense, forward-moving writes)
__global__ void append_kernel(const int* __restrict__ row, const int* __restrict__ col,
                              const float* __restrict__ ew, int* __restrict__ cur,
                              uint2* __restrict__ bucket, int E)
{
    int i = blockIdx.x * 256 + threadIdx.x;
    if (i < E) {
        int r = row[i];
        int p = atomicAdd(&cur[r >> 5], 1);
        uint2 rec;
        rec.x = __float_as_uint(ew[i]);
        rec.y = ((unsigned)(r & 31) << 16) | (unsigned)col[i];   // col < 65536
        bucket[p] = rec;
    }
}

// ---------------- fused LDS-sort + SpMM(bf16 gather) + FiLM + PReLU ----------------
// one block (512 thr) per bucket of 32 nodes; quarter-wave (16 lanes) per node
__global__ __launch_bounds__(512) void spmm_sort_film(
    const int* __restrict__ boff, const uint2* __restrict__ bucket,
    const unsigned short* __restrict__ seqb, const int* __restrict__ ntype,
    const float* __restrict__ Wg, const float* __restrict__ bg,
    const float* __restrict__ Wb, const float* __restrict__ bb,
    const float* __restrict__ bias, const float* __restrict__ prelu,
    float* __restrict__ out, int N)
{
    __shared__ uint2 sorted[32 * 64];   // 16 KiB: 32 nodes x 64 edge slots
    __shared__ int   bc[32];

    const int t = threadIdx.x;
    const int b = blockIdx.x;
    const int start = boff[b];
    const int end   = boff[b + 1];
    const int cnt   = end - start;

    if (t < 32) bc[t] = 0;
    __syncthreads();

    for (int i = t; i < cnt; i += 512) {
        uint2 rec = bucket[start + i];
        int bin = (rec.y >> 16) & 31;
        int pos = atomicAdd(&bc[bin], 1);
        if (pos < 64) sorted[(bin << 6) + pos] = rec;   // overflow -> fallback below
    }
    __syncthreads();

    const int qw = t >> 4;          // node within bucket
    const int l  = t & 15;          // feature lane
    const int node = (b << 5) + qw;
    if (node >= N) return;

    const int f0 = l * 8;
    const int deg = bc[qw];
    float a[8] = {0.f, 0.f, 0.f, 0.f, 0.f, 0.f, 0.f, 0.f};

    if (deg <= 64) {
        const uint2* sp = &sorted[qw << 6];
        int j = 0;
        for (; j + 2 <= deg; j += 2) {
            uint2 r0 = sp[j], r1 = sp[j + 1];
            float w0 = __uint_as_float(r0.x);
            float w1 = __uint_as_float(r1.x);
            const uint4 v0 = *(const uint4*)(seqb + ((size_t)(r0.y & 0xFFFFu) << 7) + f0);
            const uint4 v1 = *(const uint4*)(seqb + ((size_t)(r1.y & 0xFFFFu) << 7) + f0);
            a[0] = fmaf(w0, bfLo(v0.x), a[0]); a[1] = fmaf(w0, bfHi(v0.x), a[1]);
            a[2] = fmaf(w0, bfLo(v0.y), a[2]); a[3] = fmaf(w0, bfHi(v0.y), a[3]);
            a[4] = fmaf(w0, bfLo(v0.z), a[4]); a[5] = fmaf(w0, bfHi(v0.z), a[5]);
            a[6] = fmaf(w0, bfLo(v0.w), a[6]); a[7] = fmaf(w0, bfHi(v0.w), a[7]);
            a[0] = fmaf(w1, bfLo(v1.x), a[0]); a[1] = fmaf(w1, bfHi(v1.x), a[1]);
            a[2] = fmaf(w1, bfLo(v1.y), a[2]); a[3] = fmaf(w1, bfHi(v1.y), a[3]);
            a[4] = fmaf(w1, bfLo(v1.z), a[4]); a[5] = fmaf(w1, bfHi(v1.z), a[5]);
            a[6] = fmaf(w1, bfLo(v1.w), a[6]); a[7] = fmaf(w1, bfHi(v1.w), a[7]);
        }
        if (j < deg) {
            uint2 r0 = sp[j];
            float w0 = __uint_as_float(r0.x);
            const uint4 v0 = *(const uint4*)(seqb + ((size_t)(r0.y & 0xFFFFu) << 7) + f0);
            a[0] = fmaf(w0, bfLo(v0.x), a[0]); a[1] = fmaf(w0, bfHi(v0.x), a[1]);
            a[2] = fmaf(w0, bfLo(v0.y), a[2]); a[3] = fmaf(w0, bfHi(v0.y), a[3]);
            a[4] = fmaf(w0, bfLo(v0.z), a[4]); a[5] = fmaf(w0, bfHi(v0.z), a[5]);
            a[6] = fmaf(w0, bfLo(v0.w), a[6]); a[7] = fmaf(w0, bfHi(v0.w), a[7]);
        }
    } else {
        // exact fallback: scan bucket region from global, filter by node bits
        for (int i = start; i < end; ++i) {
            uint2 rec = bucket[i];
            if ((int)((rec.y >> 16) & 31) == qw) {
                float w = __uint_as_float(rec.x);
                const uint4 v = *(const uint4*)(seqb + ((size_t)(rec.y & 0xFFFFu) << 7) + f0);
                a[0] = fmaf(w, bfLo(v.x), a[0]); a[1] = fmaf(w, bfHi(v.x), a[1]);
                a[2] = fmaf(w, bfLo(v.y), a[2]); a[3] = fmaf(w, bfHi(v.y), a[3]);
                a[4] = fmaf(w, bfLo(v.z), a[4]); a[5] = fmaf(w, bfHi(v.z), a[5]);
                a[6] = fmaf(w, bfLo(v.w), a[6]); a[7] = fmaf(w, bfHi(v.w), a[7]);
            }
        }
    }

    // FiLM + bias + residual + PReLU epilogue
    const int tp = ntype[node];
    float4 g0 = *(const float4*)(Wg + tp * OUT_F + f0);
    float4 g1 = *(const float4*)(Wg + tp * OUT_F + f0 + 4);
    float4 h0 = *(const float4*)(bg + f0);
    float4 h1 = *(const float4*)(bg + f0 + 4);
    float4 p0 = *(const float4*)(Wb + tp * OUT_F + f0);
    float4 p1 = *(const float4*)(Wb + tp * OUT_F + f0 + 4);
    float4 q0 = *(const float4*)(bb + f0);
    float4 q1 = *(const float4*)(bb + f0 + 4);
    float4 s0 = *(const float4*)(bias + f0);
    float4 s1 = *(const float4*)(bias + f0 + 4);
    uint4  rs = *(const uint4*)(seqb + ((size_t)node << 7) + f0);
    float  sl = prelu[0];

    float gg[8] = {g0.x + h0.x, g0.y + h0.y, g0.z + h0.z, g0.w + h0.w,
                   g1.x + h1.x, g1.y + h1.y, g1.z + h1.z, g1.w + h1.w};
    float pb[8] = {p0.x + q0.x + s0.x, p0.y + q0.y + s0.y, p0.z + q0.z + s0.z, p0.w + q0.w + s0.w,
                   p1.x + q1.x + s1.x, p1.y + q1.y + s1.y, p1.z + q1.z + s1.z, p1.w + q1.w + s1.w};
    float rv[8] = {bfLo(rs.x), bfHi(rs.x), bfLo(rs.y), bfHi(rs.y),
                   bfLo(rs.z), bfHi(rs.z), bfLo(rs.w), bfHi(rs.w)};
    float oo[8];
#pragma unroll
    for (int k = 0; k < 8; ++k) {
        float v = fmaf(gg[k], a[k], pb[k]) + rv[k];
        oo[k] = (v >= 0.f) ? v : sl * v;
    }
    *(float4*)(out + ((size_t)node << 7) + f0)     = make_float4(oo[0], oo[1], oo[2], oo[3]);
    *(float4*)(out + ((size_t)node << 7) + f0 + 4) = make_float4(oo[4], oo[5], oo[6], oo[7]);
}

// ---------------- launch ----------------
extern "C" void kernel_launch(void* const* d_in, const int* in_sizes, int n_in,
                              void* d_out, int out_size, void* d_ws, size_t ws_size,
                              hipStream_t stream)
{
    const float* seq   = (const float*)d_in[0];
    const float* ew    = (const float*)d_in[1];
    const float* W_fc  = (const float*)d_in[2];
    const float* W_g   = (const float*)d_in[3];
    const float* b_g   = (const float*)d_in[4];
    const float* W_b   = (const float*)d_in[5];
    const float* b_b   = (const float*)d_in[6];
    const float* bias  = (const float*)d_in[7];
    const float* prelu = (const float*)d_in[8];
    const int*   erow  = (const int*)d_in[9];
    const int*   ecol  = (const int*)d_in[10];
    const int*   ntype = (const int*)d_in[11];
    const int N = in_sizes[11];
    const int E = in_sizes[1];
    const int NBK = (N + 31) >> 5;          // 32-node buckets

    char* ws = (char*)d_ws;
    size_t o = 0;
    unsigned short* seqb = (unsigned short*)(ws + o); o += (size_t)N * OUT_F * 2; o = (o + 15) & ~(size_t)15;
    int*   cntb = (int*)(ws + o);  o += (size_t)NBK * 4;       o = (o + 15) & ~(size_t)15;
    int*   boff = (int*)(ws + o);  o += ((size_t)NBK + 1) * 4; o = (o + 15) & ~(size_t)15;
    int*   cur  = (int*)(ws + o);  o += (size_t)NBK * 4;       o = (o + 15) & ~(size_t)15;
    uint2* bucket = (uint2*)(ws + o); o += (size_t)E * 8;

    hipLaunchKernelGGL(zerob_kernel, dim3((NBK + 255) / 256), dim3(256), 0, stream, cntb, NBK);
    hipLaunchKernelGGL(histb_kernel, dim3((E / 4 + 255) / 256 + 1), dim3(256), 0, stream, erow, cntb, E);
    hipLaunchKernelGGL(scan2_kernel, dim3(1), dim3(1024), 0, stream, cntb, boff, cur, NBK);
    hipLaunchKernelGGL(append_kernel, dim3((E + 255) / 256), dim3(256), 0, stream, erow, ecol, ew, cur, bucket, E);
    hipLaunchKernelGGL(gemm64x128, dim3((N + 63) / 64), dim3(256), 0, stream, seq, W_fc, seqb, N);
    hipLaunchKernelGGL(spmm_sort_film, dim3(NBK), dim3(512), 0, stream,
                       boff, bucket, seqb, ntype, W_g, b_g, W_b, b_b, bias, prelu, (float*)d_out, N);
}

// Round 4
// 118.163 us; speedup vs baseline: 2.6983x; 2.6983x over previous
//
#include <hip/hip_runtime.h>

#define IN_F 128
#define OUT_F 128
#define BKLOG 6
#define BKN 64            // nodes per bucket
#define SLOTS 56          // edge slots per node in LDS
#define CHUNK 8192        // edges per block in hist/scatter

static __device__ __forceinline__ unsigned f2bf(float x) {
    unsigned b = __float_as_uint(x);
    return (b + 0x7FFFu + ((b >> 16) & 1u)) >> 16;   // RNE
}
static __device__ __forceinline__ float bfLo(unsigned u) { return __uint_as_float(u << 16); }
static __device__ __forceinline__ float bfHi(unsigned u) { return __uint_as_float(u & 0xFFFF0000u); }

// ---------------- GEMM: seq_b16[N,128] = bf16( A[N,128] @ W[128,128] ) ----------------
__global__ __launch_bounds__(256) void gemm64x128(
    const float* __restrict__ A, const float* __restrict__ W,
    unsigned short* __restrict__ Cb, int nrows)
{
    __shared__ float As[64][65];
    __shared__ float Ws[64][128];
    const int t  = threadIdx.x;
    const int rg = t >> 4;
    const int c0 = (t & 15) * 8;
    const int rowBase = blockIdx.x * 64;

    float acc[4][8];
#pragma unroll
    for (int i = 0; i < 4; ++i)
#pragma unroll
        for (int j = 0; j < 8; ++j) acc[i][j] = 0.f;

    for (int p = 0; p < 2; ++p) {
#pragma unroll
        for (int i = 0; i < 4; ++i) {
            int q  = t + i * 256;
            int r  = q >> 4;
            int k4 = (q & 15) * 4;
            int gr = rowBase + r;
            if (gr >= nrows) gr = nrows - 1;
            const float4 v = *(const float4*)(A + (size_t)gr * IN_F + p * 64 + k4);
            As[r][k4 + 0] = v.x; As[r][k4 + 1] = v.y;
            As[r][k4 + 2] = v.z; As[r][k4 + 3] = v.w;
        }
#pragma unroll
        for (int i = 0; i < 8; ++i) {
            int q  = t + i * 256;
            int k  = q >> 5;
            int c4 = (q & 31) * 4;
            *(float4*)(&Ws[k][c4]) = *(const float4*)(W + (p * 64 + k) * OUT_F + c4);
        }
        __syncthreads();

#pragma unroll 4
        for (int k = 0; k < 64; ++k) {
            float av[4] = {As[rg * 4 + 0][k], As[rg * 4 + 1][k],
                           As[rg * 4 + 2][k], As[rg * 4 + 3][k]};
            float4 w0 = *(const float4*)(&Ws[k][c0]);
            float4 w1 = *(const float4*)(&Ws[k][c0 + 4]);
            float wv[8] = {w0.x, w0.y, w0.z, w0.w, w1.x, w1.y, w1.z, w1.w};
#pragma unroll
            for (int i = 0; i < 4; ++i)
#pragma unroll
                for (int j = 0; j < 8; ++j)
                    acc[i][j] = fmaf(av[i], wv[j], acc[i][j]);
        }
        __syncthreads();
    }

#pragma unroll
    for (int i = 0; i < 4; ++i) {
        int gr = rowBase + rg * 4 + i;
        if (gr < nrows) {
            uint4 pk;
            pk.x = f2bf(acc[i][0]) | (f2bf(acc[i][1]) << 16);
            pk.y = f2bf(acc[i][2]) | (f2bf(acc[i][3]) << 16);
            pk.z = f2bf(acc[i][4]) | (f2bf(acc[i][5]) << 16);
            pk.w = f2bf(acc[i][6]) | (f2bf(acc[i][7]) << 16);
            *(uint4*)(Cb + (size_t)gr * OUT_F + c0) = pk;
        }
    }
}

// ---------------- bucket CSR build (64-node buckets, block-aggregated) ----------------
__global__ void zero_kernel(int* __restrict__ c, int n)
{
    int i = blockIdx.x * 256 + threadIdx.x;
    if (i < n) c[i] = 0;
}

// LDS-privatized histogram over buckets
__global__ __launch_bounds__(256) void hist_lds(const int* __restrict__ row,
                                                int* __restrict__ cnt, int E, int NBK)
{
    __shared__ int h[1024];
    const int t = threadIdx.x;
    for (int i = t; i < NBK; i += 256) h[i] = 0;
    __syncthreads();
    const int base = blockIdx.x * CHUNK;
    const int lim  = min(CHUNK, E - base);
    for (int i = t; i < lim; i += 256)
        atomicAdd(&h[row[base + i] >> BKLOG], 1);
    __syncthreads();
    for (int i = t; i < NBK; i += 256) {
        int c = h[i];
        if (c) atomicAdd(&cnt[i], c);
    }
}

// single block scan of bucket counts -> region offsets + global cursors
__global__ __launch_bounds__(1024) void scan1_kernel(const int* __restrict__ cnt,
                                                     int* __restrict__ boff,
                                                     int* __restrict__ gcur, int NBK)
{
    __shared__ int s[1024];
    const int t = threadIdx.x;
    int v = (t < NBK) ? cnt[t] : 0;
    s[t] = v;
    __syncthreads();
    for (int o = 1; o < 1024; o <<= 1) {
        int x = (t >= o) ? s[t - o] : 0;
        __syncthreads();
        s[t] += x;
        __syncthreads();
    }
    if (t < NBK) { boff[t] = s[t] - v; gcur[t] = s[t] - v; }
    if (t == NBK - 1) boff[NBK] = s[t];
}

// block-aggregated scatter: dense per-bucket runs -> no write amplification
__global__ __launch_bounds__(256) void scatter_agg(
    const int* __restrict__ row, const int* __restrict__ col,
    const float* __restrict__ ew, int* __restrict__ gcur,
    uint2* __restrict__ bucket, int E, int NBK)
{
    __shared__ int h[1024];
    const int t = threadIdx.x;
    const int base = blockIdx.x * CHUNK;
    const int lim  = min(CHUNK, E - base);

    for (int i = t; i < NBK; i += 256) h[i] = 0;
    __syncthreads();
    for (int i = t; i < lim; i += 256)
        atomicAdd(&h[row[base + i] >> BKLOG], 1);
    __syncthreads();
    // reserve one run per touched bucket; h[] becomes the write cursor
    for (int i = t; i < NBK; i += 256) {
        int c = h[i];
        h[i] = c ? atomicAdd(&gcur[i], c) : 0;
    }
    __syncthreads();
    for (int i = t; i < lim; i += 256) {
        int r = row[base + i];
        int p = atomicAdd(&h[r >> BKLOG], 1);
        uint2 rec;
        rec.x = __float_as_uint(ew[base + i]);
        rec.y = ((unsigned)(r & (BKN - 1)) << 16) | (unsigned)col[base + i];  // col < 65536
        bucket[p] = rec;
    }
}

// ---------------- fused LDS-sort + SpMM(bf16 gather) + FiLM + PReLU ----------------
// one block (256 thr) per bucket of 64 nodes; quarter-wave (16 lanes) per node
__global__ __launch_bounds__(256) void spmm64_film(
    const int* __restrict__ boff, const uint2* __restrict__ bucket,
    const unsigned short* __restrict__ seqb, const int* __restrict__ ntype,
    const float* __restrict__ Wg, const float* __restrict__ bg,
    const float* __restrict__ Wb, const float* __restrict__ bb,
    const float* __restrict__ bias, const float* __restrict__ prelu,
    float* __restrict__ out, int N)
{
    __shared__ uint2 slot[BKN * SLOTS];   // 28 KiB
    __shared__ int   bc[BKN];

    const int t = threadIdx.x;
    const int b = blockIdx.x;
    const int start = boff[b];
    const int end   = boff[b + 1];
    const int cnt   = end - start;

    if (t < BKN) bc[t] = 0;
    __syncthreads();

    for (int i = t; i < cnt; i += 256) {
        uint2 rec = bucket[start + i];
        int n = (rec.y >> 16) & (BKN - 1);
        int pos = atomicAdd(&bc[n], 1);
        if (pos < SLOTS) slot[n * SLOTS + pos] = rec;   // overflow -> exact fallback
    }
    __syncthreads();

    const int l  = t & 15;
    const int f0 = l * 8;
    const float sl = prelu[0];

    for (int g = 0; g < 4; ++g) {
        const int nl = g * 16 + (t >> 4);
        const int node = (b << BKLOG) + nl;
        if (node >= N) continue;

        const int deg = bc[nl];
        float a[8] = {0.f, 0.f, 0.f, 0.f, 0.f, 0.f, 0.f, 0.f};

        if (deg <= SLOTS) {
            const uint2* sp = &slot[nl * SLOTS];
            int j = 0;
            for (; j + 2 <= deg; j += 2) {
                uint2 r0 = sp[j], r1 = sp[j + 1];
                float w0 = __uint_as_float(r0.x);
                float w1 = __uint_as_float(r1.x);
                const uint4 v0 = *(const uint4*)(seqb + ((size_t)(r0.y & 0xFFFFu) << 7) + f0);
                const uint4 v1 = *(const uint4*)(seqb + ((size_t)(r1.y & 0xFFFFu) << 7) + f0);
                a[0] = fmaf(w0, bfLo(v0.x), a[0]); a[1] = fmaf(w0, bfHi(v0.x), a[1]);
                a[2] = fmaf(w0, bfLo(v0.y), a[2]); a[3] = fmaf(w0, bfHi(v0.y), a[3]);
                a[4] = fmaf(w0, bfLo(v0.z), a[4]); a[5] = fmaf(w0, bfHi(v0.z), a[5]);
                a[6] = fmaf(w0, bfLo(v0.w), a[6]); a[7] = fmaf(w0, bfHi(v0.w), a[7]);
                a[0] = fmaf(w1, bfLo(v1.x), a[0]); a[1] = fmaf(w1, bfHi(v1.x), a[1]);
                a[2] = fmaf(w1, bfLo(v1.y), a[2]); a[3] = fmaf(w1, bfHi(v1.y), a[3]);
                a[4] = fmaf(w1, bfLo(v1.z), a[4]); a[5] = fmaf(w1, bfHi(v1.z), a[5]);
                a[6] = fmaf(w1, bfLo(v1.w), a[6]); a[7] = fmaf(w1, bfHi(v1.w), a[7]);
            }
            if (j < deg) {
                uint2 r0 = sp[j];
                float w0 = __uint_as_float(r0.x);
                const uint4 v0 = *(const uint4*)(seqb + ((size_t)(r0.y & 0xFFFFu) << 7) + f0);
                a[0] = fmaf(w0, bfLo(v0.x), a[0]); a[1] = fmaf(w0, bfHi(v0.x), a[1]);
                a[2] = fmaf(w0, bfLo(v0.y), a[2]); a[3] = fmaf(w0, bfHi(v0.y), a[3]);
                a[4] = fmaf(w0, bfLo(v0.z), a[4]); a[5] = fmaf(w0, bfHi(v0.z), a[5]);
                a[6] = fmaf(w0, bfLo(v0.w), a[6]); a[7] = fmaf(w0, bfHi(v0.w), a[7]);
            }
        } else {
            for (int i = start; i < end; ++i) {
                uint2 rec = bucket[i];
                if ((int)((rec.y >> 16) & (BKN - 1)) == nl) {
                    float w = __uint_as_float(rec.x);
                    const uint4 v = *(const uint4*)(seqb + ((size_t)(rec.y & 0xFFFFu) << 7) + f0);
                    a[0] = fmaf(w, bfLo(v.x), a[0]); a[1] = fmaf(w, bfHi(v.x), a[1]);
                    a[2] = fmaf(w, bfLo(v.y), a[2]); a[3] = fmaf(w, bfHi(v.y), a[3]);
                    a[4] = fmaf(w, bfLo(v.z), a[4]); a[5] = fmaf(w, bfHi(v.z), a[5]);
                    a[6] = fmaf(w, bfLo(v.w), a[6]); a[7] = fmaf(w, bfHi(v.w), a[7]);
                }
            }
        }

        const int tp = ntype[node];
        float4 g0 = *(const float4*)(Wg + tp * OUT_F + f0);
        float4 g1 = *(const float4*)(Wg + tp * OUT_F + f0 + 4);
        float4 h0 = *(const float4*)(bg + f0);
        float4 h1 = *(const float4*)(bg + f0 + 4);
        float4 p0 = *(const float4*)(Wb + tp * OUT_F + f0);
        float4 p1 = *(const float4*)(Wb + tp * OUT_F + f0 + 4);
        float4 q0 = *(const float4*)(bb + f0);
        float4 q1 = *(const float4*)(bb + f0 + 4);
        float4 s0 = *(const float4*)(bias + f0);
        float4 s1 = *(const float4*)(bias + f0 + 4);
        uint4  rs = *(const uint4*)(seqb + ((size_t)node << 7) + f0);

        float gg[8] = {g0.x + h0.x, g0.y + h0.y, g0.z + h0.z, g0.w + h0.w,
                       g1.x + h1.x, g1.y + h1.y, g1.z + h1.z, g1.w + h1.w};
        float pb[8] = {p0.x + q0.x + s0.x, p0.y + q0.y + s0.y, p0.z + q0.z + s0.z, p0.w + q0.w + s0.w,
                       p1.x + q1.x + s1.x, p1.y + q1.y + s1.y, p1.z + q1.z + s1.z, p1.w + q1.w + s1.w};
        float rv[8] = {bfLo(rs.x), bfHi(rs.x), bfLo(rs.y), bfHi(rs.y),
                       bfLo(rs.z), bfHi(rs.z), bfLo(rs.w), bfHi(rs.w)};
        float oo[8];
#pragma unroll
        for (int k = 0; k < 8; ++k) {
            float v = fmaf(gg[k], a[k], pb[k]) + rv[k];
            oo[k] = (v >= 0.f) ? v : sl * v;
        }
        *(float4*)(out + ((size_t)node << 7) + f0)     = make_float4(oo[0], oo[1], oo[2], oo[3]);
        *(float4*)(out + ((size_t)node << 7) + f0 + 4) = make_float4(oo[4], oo[5], oo[6], oo[7]);
    }
}

// ---------------- launch ----------------
extern "C" void kernel_launch(void* const* d_in, const int* in_sizes, int n_in,
                              void* d_out, int out_size, void* d_ws, size_t ws_size,
                              hipStream_t stream)
{
    const float* seq   = (const float*)d_in[0];
    const float* ew    = (const float*)d_in[1];
    const float* W_fc  = (const float*)d_in[2];
    const float* W_g   = (const float*)d_in[3];
    const float* b_g   = (const float*)d_in[4];
    const float* W_b   = (const float*)d_in[5];
    const float* b_b   = (const float*)d_in[6];
    const float* bias  = (const float*)d_in[7];
    const float* prelu = (const float*)d_in[8];
    const int*   erow  = (const int*)d_in[9];
    const int*   ecol  = (const int*)d_in[10];
    const int*   ntype = (const int*)d_in[11];
    const int N = in_sizes[11];
    const int E = in_sizes[1];
    const int NBK = (N + BKN - 1) >> BKLOG;            // 64-node buckets (<=1024)
    const int NCH = (E + CHUNK - 1) / CHUNK;           // edge chunks

    char* ws = (char*)d_ws;
    size_t o = 0;
    unsigned short* seqb = (unsigned short*)(ws + o); o += (size_t)N * OUT_F * 2; o = (o + 15) & ~(size_t)15;
    int*   cnt  = (int*)(ws + o);  o += 1024 * 4;
    int*   boff = (int*)(ws + o);  o += 1025 * 4;
    int*   gcur = (int*)(ws + o);  o += 1024 * 4 + 12; o &= ~(size_t)15;
    uint2* bucket = (uint2*)(ws + o); o += (size_t)E * 8;

    hipLaunchKernelGGL(zero_kernel, dim3((NBK + 255) / 256), dim3(256), 0, stream, cnt, NBK);
    hipLaunchKernelGGL(hist_lds, dim3(NCH), dim3(256), 0, stream, erow, cnt, E, NBK);
    hipLaunchKernelGGL(scan1_kernel, dim3(1), dim3(1024), 0, stream, cnt, boff, gcur, NBK);
    hipLaunchKernelGGL(scatter_agg, dim3(NCH), dim3(256), 0, stream, erow, ecol, ew, gcur, bucket, E, NBK);
    hipLaunchKernelGGL(gemm64x128, dim3((N + 63) / 64), dim3(256), 0, stream, seq, W_fc, seqb, N);
    hipLaunchKernelGGL(spmm64_film, dim3(NBK), dim3(256), 0, stream,
                       boff, bucket, seqb, ntype, W_g, b_g, W_b, b_b, bias, prelu, (float*)d_out, N);
}

// Round 5
// 92.156 us; speedup vs baseline: 3.4597x; 1.2822x over previous
//
#include <hip/hip_runtime.h>

#define IN_F 128
#define OUT_F 128
#define BKLOG 6
#define BKN 64            // nodes per bucket
#define CAP 2048          // fixed slot capacity per bucket (exp ~1024)
#define SLOTS 56          // edge slots per node in consumer LDS
#define CHUNK 4096        // edges per scatter block
#define SCT 512           // scatter block threads

static __device__ __forceinline__ unsigned f2bf(float x) {
    unsigned b = __float_as_uint(x);
    return (b + 0x7FFFu + ((b >> 16) & 1u)) >> 16;   // RNE
}
static __device__ __forceinline__ float bfLo(unsigned u) { return __uint_as_float(u << 16); }
static __device__ __forceinline__ float bfHi(unsigned u) { return __uint_as_float(u & 0xFFFF0000u); }

// ---------------- GEMM: seq_b16[N,128] = bf16( A[N,128] @ W[128,128] ) ----------------
__global__ __launch_bounds__(256) void gemm64x128(
    const float* __restrict__ A, const float* __restrict__ W,
    unsigned short* __restrict__ Cb, int nrows)
{
    __shared__ float As[64][65];
    __shared__ float Ws[64][128];
    const int t  = threadIdx.x;
    const int rg = t >> 4;
    const int c0 = (t & 15) * 8;
    const int rowBase = blockIdx.x * 64;

    float acc[4][8];
#pragma unroll
    for (int i = 0; i < 4; ++i)
#pragma unroll
        for (int j = 0; j < 8; ++j) acc[i][j] = 0.f;

    for (int p = 0; p < 2; ++p) {
#pragma unroll
        for (int i = 0; i < 4; ++i) {
            int q  = t + i * 256;
            int r  = q >> 4;
            int k4 = (q & 15) * 4;
            int gr = rowBase + r;
            if (gr >= nrows) gr = nrows - 1;
            const float4 v = *(const float4*)(A + (size_t)gr * IN_F + p * 64 + k4);
            As[r][k4 + 0] = v.x; As[r][k4 + 1] = v.y;
            As[r][k4 + 2] = v.z; As[r][k4 + 3] = v.w;
        }
#pragma unroll
        for (int i = 0; i < 8; ++i) {
            int q  = t + i * 256;
            int k  = q >> 5;
            int c4 = (q & 31) * 4;
            *(float4*)(&Ws[k][c4]) = *(const float4*)(W + (p * 64 + k) * OUT_F + c4);
        }
        __syncthreads();

#pragma unroll 4
        for (int k = 0; k < 64; ++k) {
            float av[4] = {As[rg * 4 + 0][k], As[rg * 4 + 1][k],
                           As[rg * 4 + 2][k], As[rg * 4 + 3][k]};
            float4 w0 = *(const float4*)(&Ws[k][c0]);
            float4 w1 = *(const float4*)(&Ws[k][c0 + 4]);
            float wv[8] = {w0.x, w0.y, w0.z, w0.w, w1.x, w1.y, w1.z, w1.w};
#pragma unroll
            for (int i = 0; i < 4; ++i)
#pragma unroll
                for (int j = 0; j < 8; ++j)
                    acc[i][j] = fmaf(av[i], wv[j], acc[i][j]);
        }
        __syncthreads();
    }

#pragma unroll
    for (int i = 0; i < 4; ++i) {
        int gr = rowBase + rg * 4 + i;
        if (gr < nrows) {
            uint4 pk;
            pk.x = f2bf(acc[i][0]) | (f2bf(acc[i][1]) << 16);
            pk.y = f2bf(acc[i][2]) | (f2bf(acc[i][3]) << 16);
            pk.z = f2bf(acc[i][4]) | (f2bf(acc[i][5]) << 16);
            pk.w = f2bf(acc[i][6]) | (f2bf(acc[i][7]) << 16);
            *(uint4*)(Cb + (size_t)gr * OUT_F + c0) = pk;
        }
    }
}

// ---------------- bucket build: zero cursors, block-aggregated scatter ----------------
__global__ void zero_kernel(int* __restrict__ c, int n)
{
    int i = blockIdx.x * 1024 + threadIdx.x;
    if (i < n) c[i] = 0;
}

// fixed-capacity bucket scatter: per-block LDS hist -> one reservation atomic per
// touched bucket -> dense run writes. Overflow (total > CAP) spills exactly to ovf.
__global__ __launch_bounds__(SCT) void scatter_fix(
    const int* __restrict__ row, const int* __restrict__ col,
    const float* __restrict__ ew, int* __restrict__ gcur,
    uint2* __restrict__ bucket, uint2* __restrict__ ovf, int E, int NBK)
{
    __shared__ int h[1024];
    const int t = threadIdx.x;
    const int base = blockIdx.x * CHUNK;
    const int lim  = min(CHUNK, E - base);

    for (int i = t; i < 1024; i += SCT) h[i] = 0;
    __syncthreads();

    int   rc[8]; float wc[8]; int cc[8];
#pragma unroll
    for (int k = 0; k < 8; ++k) {
        int i = t + k * SCT;
        if (i < lim) {
            rc[k] = row[base + i];
            wc[k] = ew[base + i];
            cc[k] = col[base + i];
            atomicAdd(&h[rc[k] >> BKLOG], 1);
        } else rc[k] = -1;
    }
    __syncthreads();

    // reserve one dense run per touched bucket; h[] becomes global write cursor
    for (int i = t; i < NBK; i += SCT) {
        int c = h[i];
        if (c) h[i] = atomicAdd(&gcur[i], c);
    }
    __syncthreads();

#pragma unroll
    for (int k = 0; k < 8; ++k) {
        if (rc[k] >= 0) {
            int r = rc[k];
            int b = r >> BKLOG;
            int p = atomicAdd(&h[b], 1);
            uint2 rec;
            rec.x = __float_as_uint(wc[k]);
            if (p < CAP) {
                rec.y = ((unsigned)(r & (BKN - 1)) << 16) | (unsigned)cc[k];
                bucket[(size_t)b * CAP + p] = rec;
            } else {
                int q = atomicAdd(&gcur[NBK], 1);
                rec.y = ((unsigned)r << 16) | (unsigned)cc[k];   // full node id (N < 65536)
                ovf[q] = rec;
            }
        }
    }
}

// ---------------- fused LDS-sort + SpMM(bf16 gather) + FiLM + PReLU ----------------
// one block (256 thr) per bucket of 64 nodes; quarter-wave (16 lanes) per node
__global__ __launch_bounds__(256) void spmm64_film(
    const int* __restrict__ gcur, const uint2* __restrict__ bucket,
    const uint2* __restrict__ ovf,
    const unsigned short* __restrict__ seqb, const int* __restrict__ ntype,
    const float* __restrict__ Wg, const float* __restrict__ bg,
    const float* __restrict__ Wb, const float* __restrict__ bb,
    const float* __restrict__ bias, const float* __restrict__ prelu,
    float* __restrict__ out, int N, int NBK)
{
    __shared__ uint2 slot[BKN * SLOTS];   // 28 KiB
    __shared__ int   bc[BKN];

    const int t = threadIdx.x;
    const int b = blockIdx.x;
    const uint2* breg = bucket + (size_t)b * CAP;
    const int total = gcur[b];
    const int inb   = min(total, CAP);

    if (t < BKN) bc[t] = 0;
    __syncthreads();

    for (int i = t; i < inb; i += 256) {
        uint2 rec = breg[i];
        int n = (rec.y >> 16) & (BKN - 1);
        int pos = atomicAdd(&bc[n], 1);
        if (pos < SLOTS) slot[n * SLOTS + pos] = rec;   // overflow -> exact fallback
    }
    __syncthreads();

    const int l  = t & 15;
    const int f0 = l * 8;
    const float sl = prelu[0];

    for (int g = 0; g < 4; ++g) {
        const int nl = g * 16 + (t >> 4);
        const int node = (b << BKLOG) + nl;
        if (node >= N) continue;

        const int deg = bc[nl];
        float a[8] = {0.f, 0.f, 0.f, 0.f, 0.f, 0.f, 0.f, 0.f};

        if (deg <= SLOTS) {
            const uint2* sp = &slot[nl * SLOTS];
            int j = 0;
            for (; j + 2 <= deg; j += 2) {
                uint2 r0 = sp[j], r1 = sp[j + 1];
                float w0 = __uint_as_float(r0.x);
                float w1 = __uint_as_float(r1.x);
                const uint4 v0 = *(const uint4*)(seqb + ((size_t)(r0.y & 0xFFFFu) << 7) + f0);
                const uint4 v1 = *(const uint4*)(seqb + ((size_t)(r1.y & 0xFFFFu) << 7) + f0);
                a[0] = fmaf(w0, bfLo(v0.x), a[0]); a[1] = fmaf(w0, bfHi(v0.x), a[1]);
                a[2] = fmaf(w0, bfLo(v0.y), a[2]); a[3] = fmaf(w0, bfHi(v0.y), a[3]);
                a[4] = fmaf(w0, bfLo(v0.z), a[4]); a[5] = fmaf(w0, bfHi(v0.z), a[5]);
                a[6] = fmaf(w0, bfLo(v0.w), a[6]); a[7] = fmaf(w0, bfHi(v0.w), a[7]);
                a[0] = fmaf(w1, bfLo(v1.x), a[0]); a[1] = fmaf(w1, bfHi(v1.x), a[1]);
                a[2] = fmaf(w1, bfLo(v1.y), a[2]); a[3] = fmaf(w1, bfHi(v1.y), a[3]);
                a[4] = fmaf(w1, bfLo(v1.z), a[4]); a[5] = fmaf(w1, bfHi(v1.z), a[5]);
                a[6] = fmaf(w1, bfLo(v1.w), a[6]); a[7] = fmaf(w1, bfHi(v1.w), a[7]);
            }
            if (j < deg) {
                uint2 r0 = sp[j];
                float w0 = __uint_as_float(r0.x);
                const uint4 v0 = *(const uint4*)(seqb + ((size_t)(r0.y & 0xFFFFu) << 7) + f0);
                a[0] = fmaf(w0, bfLo(v0.x), a[0]); a[1] = fmaf(w0, bfHi(v0.x), a[1]);
                a[2] = fmaf(w0, bfLo(v0.y), a[2]); a[3] = fmaf(w0, bfHi(v0.y), a[3]);
                a[4] = fmaf(w0, bfLo(v0.z), a[4]); a[5] = fmaf(w0, bfHi(v0.z), a[5]);
                a[6] = fmaf(w0, bfLo(v0.w), a[6]); a[7] = fmaf(w0, bfHi(v0.w), a[7]);
            }
        } else {
            // exact fallback: rescan in-bucket region for this node
            for (int i = 0; i < inb; ++i) {
                uint2 rec = breg[i];
                if ((int)((rec.y >> 16) & (BKN - 1)) == nl) {
                    float w = __uint_as_float(rec.x);
                    const uint4 v = *(const uint4*)(seqb + ((size_t)(rec.y & 0xFFFFu) << 7) + f0);
                    a[0] = fmaf(w, bfLo(v.x), a[0]); a[1] = fmaf(w, bfHi(v.x), a[1]);
                    a[2] = fmaf(w, bfLo(v.y), a[2]); a[3] = fmaf(w, bfHi(v.y), a[3]);
                    a[4] = fmaf(w, bfLo(v.z), a[4]); a[5] = fmaf(w, bfHi(v.z), a[5]);
                    a[6] = fmaf(w, bfLo(v.w), a[6]); a[7] = fmaf(w, bfHi(v.w), a[7]);
                }
            }
        }
        if (total > CAP) {
            // this bucket spilled: pick up this node's records from the spill list
            const int novf = gcur[NBK];
            for (int i = 0; i < novf; ++i) {
                uint2 rec = ovf[i];
                if ((int)(rec.y >> 16) == node) {
                    float w = __uint_as_float(rec.x);
                    const uint4 v = *(const uint4*)(seqb + ((size_t)(rec.y & 0xFFFFu) << 7) + f0);
                    a[0] = fmaf(w, bfLo(v.x), a[0]); a[1] = fmaf(w, bfHi(v.x), a[1]);
                    a[2] = fmaf(w, bfLo(v.y), a[2]); a[3] = fmaf(w, bfHi(v.y), a[3]);
                    a[4] = fmaf(w, bfLo(v.z), a[4]); a[5] = fmaf(w, bfHi(v.z), a[5]);
                    a[6] = fmaf(w, bfLo(v.w), a[6]); a[7] = fmaf(w, bfHi(v.w), a[7]);
                }
            }
        }

        const int tp = ntype[node];
        float4 g0 = *(const float4*)(Wg + tp * OUT_F + f0);
        float4 g1 = *(const float4*)(Wg + tp * OUT_F + f0 + 4);
        float4 h0 = *(const float4*)(bg + f0);
        float4 h1 = *(const float4*)(bg + f0 + 4);
        float4 p0 = *(const float4*)(Wb + tp * OUT_F + f0);
        float4 p1 = *(const float4*)(Wb + tp * OUT_F + f0 + 4);
        float4 q0 = *(const float4*)(bb + f0);
        float4 q1 = *(const float4*)(bb + f0 + 4);
        float4 s0 = *(const float4*)(bias + f0);
        float4 s1 = *(const float4*)(bias + f0 + 4);
        uint4  rs = *(const uint4*)(seqb + ((size_t)node << 7) + f0);

        float gg[8] = {g0.x + h0.x, g0.y + h0.y, g0.z + h0.z, g0.w + h0.w,
                       g1.x + h1.x, g1.y + h1.y, g1.z + h1.z, g1.w + h1.w};
        float pb[8] = {p0.x + q0.x + s0.x, p0.y + q0.y + s0.y, p0.z + q0.z + s0.z, p0.w + q0.w + s0.w,
                       p1.x + q1.x + s1.x, p1.y + q1.y + s1.y, p1.z + q1.z + s1.z, p1.w + q1.w + s1.w};
        float rv[8] = {bfLo(rs.x), bfHi(rs.x), bfLo(rs.y), bfHi(rs.y),
                       bfLo(rs.z), bfHi(rs.z), bfLo(rs.w), bfHi(rs.w)};
        float oo[8];
#pragma unroll
        for (int k = 0; k < 8; ++k) {
            float v = fmaf(gg[k], a[k], pb[k]) + rv[k];
            oo[k] = (v >= 0.f) ? v : sl * v;
        }
        *(float4*)(out + ((size_t)node << 7) + f0)     = make_float4(oo[0], oo[1], oo[2], oo[3]);
        *(float4*)(out + ((size_t)node << 7) + f0 + 4) = make_float4(oo[4], oo[5], oo[6], oo[7]);
    }
}

// ---------------- launch ----------------
extern "C" void kernel_launch(void* const* d_in, const int* in_sizes, int n_in,
                              void* d_out, int out_size, void* d_ws, size_t ws_size,
                              hipStream_t stream)
{
    const float* seq   = (const float*)d_in[0];
    const float* ew    = (const float*)d_in[1];
    const float* W_fc  = (const float*)d_in[2];
    const float* W_g   = (const float*)d_in[3];
    const float* b_g   = (const float*)d_in[4];
    const float* W_b   = (const float*)d_in[5];
    const float* b_b   = (const float*)d_in[6];
    const float* bias  = (const float*)d_in[7];
    const float* prelu = (const float*)d_in[8];
    const int*   erow  = (const int*)d_in[9];
    const int*   ecol  = (const int*)d_in[10];
    const int*   ntype = (const int*)d_in[11];
    const int N = in_sizes[11];
    const int E = in_sizes[1];
    const int NBK = (N + BKN - 1) >> BKLOG;            // 64-node buckets (<=1024)
    const int NCH = (E + CHUNK - 1) / CHUNK;           // scatter chunks

    char* ws = (char*)d_ws;
    size_t o = 0;
    unsigned short* seqb = (unsigned short*)(ws + o); o += (size_t)N * OUT_F * 2; o = (o + 15) & ~(size_t)15;
    int*   gcur = (int*)(ws + o);  o += 1025 * 4 + 12; o &= ~(size_t)15;
    uint2* bucket = (uint2*)(ws + o); o += (size_t)NBK * CAP * 8;
    uint2* ovf    = (uint2*)(ws + o); o += (size_t)E * 8;

    hipLaunchKernelGGL(zero_kernel, dim3(1), dim3(1024), 0, stream, gcur, NBK + 1);
    hipLaunchKernelGGL(scatter_fix, dim3(NCH), dim3(SCT), 0, stream,
                       erow, ecol, ew, gcur, bucket, ovf, E, NBK);
    hipLaunchKernelGGL(gemm64x128, dim3((N + 63) / 64), dim3(256), 0, stream, seq, W_fc, seqb, N);
    hipLaunchKernelGGL(spmm64_film, dim3(NBK), dim3(256), 0, stream,
                       gcur, bucket, ovf, seqb, ntype, W_g, b_g, W_b, b_b, bias, prelu,
                       (float*)d_out, N, NBK);
}

// Round 6
// 69.558 us; speedup vs baseline: 4.5837x; 1.3249x over previous
//
#include <hip/hip_runtime.h>

#define IN_F 128
#define OUT_F 128
#define BKLOG 6
#define BKN 64            // nodes per bucket
#define CAP 2048          // fixed slot capacity per bucket (exp ~1024)
#define SLOTS 56          // edge slots per node in consumer LDS
#define CHUNK 4096        // edges per scatter block
#define SCT 512           // scatter block threads

typedef __attribute__((ext_vector_type(8))) short short8v;
typedef __attribute__((ext_vector_type(4))) float float4v;

static __device__ __forceinline__ unsigned f2bf(float x) {
    unsigned b = __float_as_uint(x);
    return (b + 0x7FFFu + ((b >> 16) & 1u)) >> 16;   // RNE
}
static __device__ __forceinline__ float bfLo(unsigned u) { return __uint_as_float(u << 16); }
static __device__ __forceinline__ float bfHi(unsigned u) { return __uint_as_float(u & 0xFFFF0000u); }

// ---------------- prep: W^T -> bf16 (Wt[c][k]) + zero bucket cursors ----------------
__global__ __launch_bounds__(256) void prep_kernel(const float* __restrict__ W,
                                                   unsigned short* __restrict__ Wt,
                                                   int* __restrict__ gcur, int NBK)
{
    const int b = blockIdx.x;
    if (b < 64) {
        int i = b * 256 + threadIdx.x;      // 0..16383, consecutive c: coalesced read
        int k = i >> 7, c = i & 127;
        Wt[c * 128 + k] = (unsigned short)f2bf(W[i]);
    } else {
        for (int i = threadIdx.x; i <= NBK; i += 256) gcur[i] = 0;
    }
}

// ---------------- GEMM via MFMA: seq_b16[N,128] = bf16( A @ W ) ----------------
// 64 rows/block, 4 waves; wave w computes rows 16w..16w+15 x all 128 cols.
__global__ __launch_bounds__(256) void gemm_mfma(
    const float* __restrict__ A, const unsigned short* __restrict__ Wt,
    unsigned short* __restrict__ Cb, int nrows)
{
    __shared__ unsigned short Al[64][136];    // 64 rows x 128 k bf16 (+8 pad)
    __shared__ unsigned short Wl[128][136];   // 128 cols x 128 k bf16 (+8 pad)
    const int t = threadIdx.x;
    const int rowBase = blockIdx.x * 64;

    // stage W^T (bf16, already transposed): 2048 x 8-elem chunks
#pragma unroll
    for (int i = 0; i < 8; ++i) {
        int q  = t + i * 256;
        int c  = q >> 4;
        int kb = (q & 15) * 8;
        *(uint4*)(&Wl[c][kb]) = *(const uint4*)(Wt + c * 128 + kb);
    }
    // stage A rows, fp32 -> bf16 packed
#pragma unroll
    for (int i = 0; i < 8; ++i) {
        int q  = t + i * 256;
        int r  = q >> 5;
        int k4 = (q & 31) * 4;
        int gr = rowBase + r;
        if (gr >= nrows) gr = nrows - 1;
        float4 v = *(const float4*)(A + (size_t)gr * IN_F + k4);
        uint2 pk;
        pk.x = f2bf(v.x) | (f2bf(v.y) << 16);
        pk.y = f2bf(v.z) | (f2bf(v.w) << 16);
        *(uint2*)(&Al[r][k4]) = pk;
    }
    __syncthreads();

    const int w    = t >> 6;
    const int lane = t & 63;
    const int rb   = w * 16;
    const int m    = lane & 15;            // A row / B col within tile
    const int kg   = (lane >> 4) * 8;      // k-group base

    float4v acc[8];
#pragma unroll
    for (int n = 0; n < 8; ++n) acc[n] = (float4v){0.f, 0.f, 0.f, 0.f};

#pragma unroll
    for (int ks = 0; ks < 4; ++ks) {
        short8v a = *(const short8v*)(&Al[rb + m][ks * 32 + kg]);
#pragma unroll
        for (int n = 0; n < 8; ++n) {
            short8v bf = *(const short8v*)(&Wl[n * 16 + m][ks * 32 + kg]);
            acc[n] = __builtin_amdgcn_mfma_f32_16x16x32_bf16(a, bf, acc[n], 0, 0, 0);
        }
    }

    // C/D layout: col = lane&15, row = (lane>>4)*4 + j
    const int orow = rowBase + rb + (lane >> 4) * 4;
#pragma unroll
    for (int n = 0; n < 8; ++n) {
#pragma unroll
        for (int j = 0; j < 4; ++j) {
            int r = orow + j;
            if (r < nrows)
                Cb[(size_t)r * OUT_F + n * 16 + m] = (unsigned short)f2bf(acc[n][j]);
        }
    }
}

// ---------------- bucket build: block-aggregated fixed-capacity scatter ----------------
__global__ __launch_bounds__(SCT) void scatter_fix(
    const int* __restrict__ row, const int* __restrict__ col,
    const float* __restrict__ ew, int* __restrict__ gcur,
    uint2* __restrict__ bucket, uint2* __restrict__ ovf, int E, int NBK)
{
    __shared__ int h[1024];
    const int t = threadIdx.x;
    const int base = blockIdx.x * CHUNK;
    const int lim  = min(CHUNK, E - base);

    for (int i = t; i < 1024; i += SCT) h[i] = 0;
    __syncthreads();

    int   rc[8]; float wc[8]; int cc[8];
#pragma unroll
    for (int k = 0; k < 8; ++k) {
        int i = t + k * SCT;
        if (i < lim) {
            rc[k] = row[base + i];
            wc[k] = ew[base + i];
            cc[k] = col[base + i];
            atomicAdd(&h[rc[k] >> BKLOG], 1);
        } else rc[k] = -1;
    }
    __syncthreads();

    for (int i = t; i < NBK; i += SCT) {
        int c = h[i];
        if (c) h[i] = atomicAdd(&gcur[i], c);
    }
    __syncthreads();

#pragma unroll
    for (int k = 0; k < 8; ++k) {
        if (rc[k] >= 0) {
            int r = rc[k];
            int b = r >> BKLOG;
            int p = atomicAdd(&h[b], 1);
            uint2 rec;
            rec.x = __float_as_uint(wc[k]);
            if (p < CAP) {
                rec.y = ((unsigned)(r & (BKN - 1)) << 16) | (unsigned)cc[k];
                bucket[(size_t)b * CAP + p] = rec;
            } else {
                int q = atomicAdd(&gcur[NBK], 1);
                rec.y = ((unsigned)r << 16) | (unsigned)cc[k];   // full node id (N < 65536)
                ovf[q] = rec;
            }
        }
    }
}

// ---------------- fused LDS-sort + SpMM(bf16 gather) + FiLM + PReLU ----------------
__global__ __launch_bounds__(256) void spmm64_film(
    const int* __restrict__ gcur, const uint2* __restrict__ bucket,
    const uint2* __restrict__ ovf,
    const unsigned short* __restrict__ seqb, const int* __restrict__ ntype,
    const float* __restrict__ Wg, const float* __restrict__ bg,
    const float* __restrict__ Wb, const float* __restrict__ bb,
    const float* __restrict__ bias, const float* __restrict__ prelu,
    float* __restrict__ out, int N, int NBK)
{
    __shared__ uint2 slot[BKN * SLOTS];   // 28 KiB
    __shared__ int   bc[BKN];

    const int t = threadIdx.x;
    const int b = blockIdx.x;
    const uint2* breg = bucket + (size_t)b * CAP;
    const int total = gcur[b];
    const int inb   = min(total, CAP);

    if (t < BKN) bc[t] = 0;
    __syncthreads();

    for (int i = t; i < inb; i += 256) {
        uint2 rec = breg[i];
        int n = (rec.y >> 16) & (BKN - 1);
        int pos = atomicAdd(&bc[n], 1);
        if (pos < SLOTS) slot[n * SLOTS + pos] = rec;   // overflow -> exact fallback
    }
    __syncthreads();

    const int l  = t & 15;
    const int f0 = l * 8;
    const float sl = prelu[0];

    for (int g = 0; g < 4; ++g) {
        const int nl = g * 16 + (t >> 4);
        const int node = (b << BKLOG) + nl;
        if (node >= N) continue;

        const int deg = bc[nl];
        float a[8] = {0.f, 0.f, 0.f, 0.f, 0.f, 0.f, 0.f, 0.f};

        if (deg <= SLOTS) {
            const uint2* sp = &slot[nl * SLOTS];
            int j = 0;
            for (; j + 2 <= deg; j += 2) {
                uint2 r0 = sp[j], r1 = sp[j + 1];
                float w0 = __uint_as_float(r0.x);
                float w1 = __uint_as_float(r1.x);
                const uint4 v0 = *(const uint4*)(seqb + ((size_t)(r0.y & 0xFFFFu) << 7) + f0);
                const uint4 v1 = *(const uint4*)(seqb + ((size_t)(r1.y & 0xFFFFu) << 7) + f0);
                a[0] = fmaf(w0, bfLo(v0.x), a[0]); a[1] = fmaf(w0, bfHi(v0.x), a[1]);
                a[2] = fmaf(w0, bfLo(v0.y), a[2]); a[3] = fmaf(w0, bfHi(v0.y), a[3]);
                a[4] = fmaf(w0, bfLo(v0.z), a[4]); a[5] = fmaf(w0, bfHi(v0.z), a[5]);
                a[6] = fmaf(w0, bfLo(v0.w), a[6]); a[7] = fmaf(w0, bfHi(v0.w), a[7]);
                a[0] = fmaf(w1, bfLo(v1.x), a[0]); a[1] = fmaf(w1, bfHi(v1.x), a[1]);
                a[2] = fmaf(w1, bfLo(v1.y), a[2]); a[3] = fmaf(w1, bfHi(v1.y), a[3]);
                a[4] = fmaf(w1, bfLo(v1.z), a[4]); a[5] = fmaf(w1, bfHi(v1.z), a[5]);
                a[6] = fmaf(w1, bfLo(v1.w), a[6]); a[7] = fmaf(w1, bfHi(v1.w), a[7]);
            }
            if (j < deg) {
                uint2 r0 = sp[j];
                float w0 = __uint_as_float(r0.x);
                const uint4 v0 = *(const uint4*)(seqb + ((size_t)(r0.y & 0xFFFFu) << 7) + f0);
                a[0] = fmaf(w0, bfLo(v0.x), a[0]); a[1] = fmaf(w0, bfHi(v0.x), a[1]);
                a[2] = fmaf(w0, bfLo(v0.y), a[2]); a[3] = fmaf(w0, bfHi(v0.y), a[3]);
                a[4] = fmaf(w0, bfLo(v0.z), a[4]); a[5] = fmaf(w0, bfHi(v0.z), a[5]);
                a[6] = fmaf(w0, bfLo(v0.w), a[6]); a[7] = fmaf(w0, bfHi(v0.w), a[7]);
            }
        } else {
            for (int i = 0; i < inb; ++i) {
                uint2 rec = breg[i];
                if ((int)((rec.y >> 16) & (BKN - 1)) == nl) {
                    float w = __uint_as_float(rec.x);
                    const uint4 v = *(const uint4*)(seqb + ((size_t)(rec.y & 0xFFFFu) << 7) + f0);
                    a[0] = fmaf(w, bfLo(v.x), a[0]); a[1] = fmaf(w, bfHi(v.x), a[1]);
                    a[2] = fmaf(w, bfLo(v.y), a[2]); a[3] = fmaf(w, bfHi(v.y), a[3]);
                    a[4] = fmaf(w, bfLo(v.z), a[4]); a[5] = fmaf(w, bfHi(v.z), a[5]);
                    a[6] = fmaf(w, bfLo(v.w), a[6]); a[7] = fmaf(w, bfHi(v.w), a[7]);
                }
            }
        }
        if (total > CAP) {
            const int novf = gcur[NBK];
            for (int i = 0; i < novf; ++i) {
                uint2 rec = ovf[i];
                if ((int)(rec.y >> 16) == node) {
                    float w = __uint_as_float(rec.x);
                    const uint4 v = *(const uint4*)(seqb + ((size_t)(rec.y & 0xFFFFu) << 7) + f0);
                    a[0] = fmaf(w, bfLo(v.x), a[0]); a[1] = fmaf(w, bfHi(v.x), a[1]);
                    a[2] = fmaf(w, bfLo(v.y), a[2]); a[3] = fmaf(w, bfHi(v.y), a[3]);
                    a[4] = fmaf(w, bfLo(v.z), a[4]); a[5] = fmaf(w, bfHi(v.z), a[5]);
                    a[6] = fmaf(w, bfLo(v.w), a[6]); a[7] = fmaf(w, bfHi(v.w), a[7]);
                }
            }
        }

        const int tp = ntype[node];
        float4 g0 = *(const float4*)(Wg + tp * OUT_F + f0);
        float4 g1 = *(const float4*)(Wg + tp * OUT_F + f0 + 4);
        float4 h0 = *(const float4*)(bg + f0);
        float4 h1 = *(const float4*)(bg + f0 + 4);
        float4 p0 = *(const float4*)(Wb + tp * OUT_F + f0);
        float4 p1 = *(const float4*)(Wb + tp * OUT_F + f0 + 4);
        float4 q0 = *(const float4*)(bb + f0);
        float4 q1 = *(const float4*)(bb + f0 + 4);
        float4 s0 = *(const float4*)(bias + f0);
        float4 s1 = *(const float4*)(bias + f0 + 4);
        uint4  rs = *(const uint4*)(seqb + ((size_t)node << 7) + f0);

        float gg[8] = {g0.x + h0.x, g0.y + h0.y, g0.z + h0.z, g0.w + h0.w,
                       g1.x + h1.x, g1.y + h1.y, g1.z + h1.z, g1.w + h1.w};
        float pb[8] = {p0.x + q0.x + s0.x, p0.y + q0.y + s0.y, p0.z + q0.z + s0.z, p0.w + q0.w + s0.w,
                       p1.x + q1.x + s1.x, p1.y + q1.y + s1.y, p1.z + q1.z + s1.z, p1.w + q1.w + s1.w};
        float rv[8] = {bfLo(rs.x), bfHi(rs.x), bfLo(rs.y), bfHi(rs.y),
                       bfLo(rs.z), bfHi(rs.z), bfLo(rs.w), bfHi(rs.w)};
        float oo[8];
#pragma unroll
        for (int k = 0; k < 8; ++k) {
            float v = fmaf(gg[k], a[k], pb[k]) + rv[k];
            oo[k] = (v >= 0.f) ? v : sl * v;
        }
        *(float4*)(out + ((size_t)node << 7) + f0)     = make_float4(oo[0], oo[1], oo[2], oo[3]);
        *(float4*)(out + ((size_t)node << 7) + f0 + 4) = make_float4(oo[4], oo[5], oo[6], oo[7]);
    }
}

// ---------------- launch ----------------
extern "C" void kernel_launch(void* const* d_in, const int* in_sizes, int n_in,
                              void* d_out, int out_size, void* d_ws, size_t ws_size,
                              hipStream_t stream)
{
    const float* seq   = (const float*)d_in[0];
    const float* ew    = (const float*)d_in[1];
    const float* W_fc  = (const float*)d_in[2];
    const float* W_g   = (const float*)d_in[3];
    const float* b_g   = (const float*)d_in[4];
    const float* W_b   = (const float*)d_in[5];
    const float* b_b   = (const float*)d_in[6];
    const float* bias  = (const float*)d_in[7];
    const float* prelu = (const float*)d_in[8];
    const int*   erow  = (const int*)d_in[9];
    const int*   ecol  = (const int*)d_in[10];
    const int*   ntype = (const int*)d_in[11];
    const int N = in_sizes[11];
    const int E = in_sizes[1];
    const int NBK = (N + BKN - 1) >> BKLOG;            // 64-node buckets
    const int NCH = (E + CHUNK - 1) / CHUNK;           // scatter chunks

    char* ws = (char*)d_ws;
    size_t o = 0;
    unsigned short* seqb = (unsigned short*)(ws + o); o += (size_t)N * OUT_F * 2; o = (o + 15) & ~(size_t)15;
    unsigned short* Wt   = (unsigned short*)(ws + o); o += (size_t)IN_F * OUT_F * 2;
    int*   gcur = (int*)(ws + o);  o += 1025 * 4 + 12; o &= ~(size_t)15;
    uint2* bucket = (uint2*)(ws + o); o += (size_t)NBK * CAP * 8;
    uint2* ovf    = (uint2*)(ws + o); o += (size_t)E * 8;

    hipLaunchKernelGGL(prep_kernel, dim3(65), dim3(256), 0, stream, W_fc, Wt, gcur, NBK);
    hipLaunchKernelGGL(scatter_fix, dim3(NCH), dim3(SCT), 0, stream,
                       erow, ecol, ew, gcur, bucket, ovf, E, NBK);
    hipLaunchKernelGGL(gemm_mfma, dim3((N + 63) / 64), dim3(256), 0, stream, seq, Wt, seqb, N);
    hipLaunchKernelGGL(spmm64_film, dim3(NBK), dim3(256), 0, stream,
                       gcur, bucket, ovf, seqb, ntype, W_g, b_g, W_b, b_b, bias, prelu,
                       (float*)d_out, N, NBK);
}